// Round 5
// baseline (504.016 us; speedup 1.0000x reference)
//
#include <hip/hip_runtime.h>
#include <hip/hip_bf16.h>

#define NB   8
#define NTOK 1024
#define DDIM 1024
#define NEXP 16
#define HDIM 4096
#define CAP  80
#define BK   64
#define LDA  (BK + 8)

using bf16x8 = __attribute__((ext_vector_type(8))) __bf16;
using bf16x4 = __attribute__((ext_vector_type(4))) __bf16;
using f32x4  = __attribute__((ext_vector_type(4))) float;

// ---------------- GEMM1, wide-N blocks (512 cols = 2KB/row W chunks), z=4 ----
// Hpart[z][b][m][h] = sum_{k in z-slice} X[b][m][k] * W1[e][k][h]
// 512 thr = 8 waves; each wave owns 64 h-cols (4 n-tiles), block owns 512 cols.
// W1 fragments read DIRECT from global: block-aggregate footprint per k-row is
// 2KB contiguous -> spans many HBM channel-interleave slots (vs 256-512B before).
// A (X) staged in LDS bf16, double-buffered (proven pattern).
__global__ __launch_bounds__(512) void moe_g1(
    const float* __restrict__ X, const int* __restrict__ Y,
    const float* __restrict__ W1, float* __restrict__ Hpart)
{
    const int b   = blockIdx.y;
    const int e   = Y[b] & (NEXP - 1);
    const int hc  = blockIdx.x;                  // 0..7 : 512-col chunk
    const int kz  = blockIdx.z * 256;            // z in 0..3, K=256 per block
    const int tid = threadIdx.x;
    const int w   = tid >> 6;                    // wave 0..7
    const int l   = tid & 63;
    const int q   = l >> 4;
    const int r   = l & 15;
    const int n0  = hc * 512 + w * 64;           // wave's first col

    __shared__ __bf16 As[2][CAP][LDA];           // 23 KB

    const float* Xb  = X  + (size_t)b * NTOK * DDIM;
    const float* W1e = W1 + (size_t)e * DDIM * HDIM;

    f32x4 acc[5][4];                             // [m-tile][n-tile]
    #pragma unroll
    for (int i = 0; i < 5; ++i)
        #pragma unroll
        for (int j = 0; j < 4; ++j) acc[i][j] = f32x4{0.f, 0.f, 0.f, 0.f};

    // A-stage map: 80 rows x 16 k-groups (float4) = 1280 chunks over 512 thr
    float4 a_reg[3];
    #pragma unroll
    for (int it = 0; it < 3; ++it) {
        int idx = tid + 512 * it;
        if (it < 2 || idx < CAP * 16) {
            int row = idx >> 4, kg = idx & 15;
            a_reg[it] = *(const float4*)&Xb[(size_t)row * DDIM + kz + kg * 4];
        }
    }

    int cur = 0;
    for (int t = 0; t < 4; ++t) {                // 4 k-tiles of 64
        const int k0 = kz + t * BK;

        #pragma unroll
        for (int it = 0; it < 3; ++it) {
            int idx = tid + 512 * it;
            if (it < 2 || idx < CAP * 16) {
                int row = idx >> 4, kg = idx & 15;
                float4 v = a_reg[it];
                bf16x4 p = {(__bf16)v.x, (__bf16)v.y, (__bf16)v.z, (__bf16)v.w};
                *(bf16x4*)&As[cur][row][kg * 4] = p;
            }
        }
        __syncthreads();

        if (t + 1 < 4) {                         // prefetch next A tile
            const int kn = kz + (t + 1) * BK;
            #pragma unroll
            for (int it = 0; it < 3; ++it) {
                int idx = tid + 512 * it;
                if (it < 2 || idx < CAP * 16) {
                    int row = idx >> 4, kg = idx & 15;
                    a_reg[it] = *(const float4*)&Xb[(size_t)row * DDIM + kn + kg * 4];
                }
            }
        }

        #pragma unroll
        for (int s = 0; s < 2; ++s) {
            #pragma unroll
            for (int nt = 0; nt < 4; ++nt) {
                // B fragment direct from global fp32 (8 rows x 64B-coalesced)
                const float* bp = W1e + (size_t)(k0 + s * 32 + q * 8) * HDIM + n0 + nt * 16 + r;
                float bv[8];
                #pragma unroll
                for (int j = 0; j < 8; ++j) bv[j] = bp[(size_t)j * HDIM];
                bf16x8 bf;
                #pragma unroll
                for (int j = 0; j < 8; ++j) bf[j] = (__bf16)bv[j];
                #pragma unroll
                for (int mt = 0; mt < 5; ++mt) {
                    bf16x8 af = *(const bf16x8*)&As[cur][mt * 16 + r][s * 32 + q * 8];
                    acc[mt][nt] = __builtin_amdgcn_mfma_f32_16x16x32_bf16(af, bf, acc[mt][nt], 0, 0, 0);
                }
            }
        }
        __syncthreads();
        cur ^= 1;
    }

    float* Hp = Hpart + ((size_t)(blockIdx.z * NB + b) * CAP) * HDIM;
    #pragma unroll
    for (int mt = 0; mt < 5; ++mt)
        #pragma unroll
        for (int nt = 0; nt < 4; ++nt)
            #pragma unroll
            for (int v = 0; v < 4; ++v) {
                int m = mt * 16 + q * 4 + v;
                Hp[(size_t)m * HDIM + n0 + nt * 16 + r] = acc[mt][nt][v];
            }
}

// ---------------- reduce z=4 + exact GELU -> bf16 ----------------
__global__ __launch_bounds__(256) void gelu_red(const float* __restrict__ Hpart,
                                                __bf16* __restrict__ Hid)
{
    size_t i4 = (size_t)blockIdx.x * 256 + threadIdx.x;   // over 8*80*4096/4
    const size_t SL = (size_t)NB * CAP * HDIM;
    float4 s = *(const float4*)&Hpart[i4 * 4];
    #pragma unroll
    for (int z = 1; z < 4; ++z) {
        float4 v = *(const float4*)&Hpart[(size_t)z * SL + i4 * 4];
        s.x += v.x; s.y += v.y; s.z += v.z; s.w += v.w;
    }
    float a[4] = {s.x, s.y, s.z, s.w};
    bf16x4 p;
    #pragma unroll
    for (int j = 0; j < 4; ++j) {
        float x = a[j];
        p[j] = (__bf16)(0.5f * x * (1.0f + erff(x * 0.70710678118654752f)));
    }
    *(bf16x4*)&Hid[i4 * 4] = p;
}

// ---------------- GEMM2, wide-N blocks (512 cols), z=16 ----------------
// Opart[z][b][m][d] partials; W2 read = 2KB/row chunks over 256 contiguous rows
// (512 KB near-sequential stream per block).
__global__ __launch_bounds__(512) void moe_g2(
    const __bf16* __restrict__ Hid, const int* __restrict__ Y,
    const float* __restrict__ W2, float* __restrict__ Opart)
{
    const int b   = blockIdx.y;
    const int e   = Y[b] & (NEXP - 1);
    const int dc  = blockIdx.x;                  // 0..1 : 512-col chunk
    const int kz  = blockIdx.z * 256;            // z in 0..15
    const int tid = threadIdx.x;
    const int w   = tid >> 6;
    const int l   = tid & 63;
    const int q   = l >> 4;
    const int r   = l & 15;
    const int n0  = dc * 512 + w * 64;

    __shared__ __bf16 As[2][CAP][LDA];

    const __bf16* Hb  = Hid + (size_t)b * CAP * HDIM;
    const float*  W2e = W2  + (size_t)e * HDIM * DDIM;

    f32x4 acc[5][4];
    #pragma unroll
    for (int i = 0; i < 5; ++i)
        #pragma unroll
        for (int j = 0; j < 4; ++j) acc[i][j] = f32x4{0.f, 0.f, 0.f, 0.f};

    uint2 a_reg[3];                              // 4 bf16 per chunk
    #pragma unroll
    for (int it = 0; it < 3; ++it) {
        int idx = tid + 512 * it;
        if (it < 2 || idx < CAP * 16) {
            int row = idx >> 4, kg = idx & 15;
            a_reg[it] = *(const uint2*)&Hb[(size_t)row * HDIM + kz + kg * 4];
        }
    }

    int cur = 0;
    for (int t = 0; t < 4; ++t) {
        const int k0 = kz + t * BK;

        #pragma unroll
        for (int it = 0; it < 3; ++it) {
            int idx = tid + 512 * it;
            if (it < 2 || idx < CAP * 16) {
                int row = idx >> 4, kg = idx & 15;
                *(uint2*)&As[cur][row][kg * 4] = a_reg[it];
            }
        }
        __syncthreads();

        if (t + 1 < 4) {
            const int kn = kz + (t + 1) * BK;
            #pragma unroll
            for (int it = 0; it < 3; ++it) {
                int idx = tid + 512 * it;
                if (it < 2 || idx < CAP * 16) {
                    int row = idx >> 4, kg = idx & 15;
                    a_reg[it] = *(const uint2*)&Hb[(size_t)row * HDIM + kn + kg * 4];
                }
            }
        }

        #pragma unroll
        for (int s = 0; s < 2; ++s) {
            #pragma unroll
            for (int nt = 0; nt < 4; ++nt) {
                const float* bp = W2e + (size_t)(k0 + s * 32 + q * 8) * DDIM + n0 + nt * 16 + r;
                float bv[8];
                #pragma unroll
                for (int j = 0; j < 8; ++j) bv[j] = bp[(size_t)j * DDIM];
                bf16x8 bf;
                #pragma unroll
                for (int j = 0; j < 8; ++j) bf[j] = (__bf16)bv[j];
                #pragma unroll
                for (int mt = 0; mt < 5; ++mt) {
                    bf16x8 af = *(const bf16x8*)&As[cur][mt * 16 + r][s * 32 + q * 8];
                    acc[mt][nt] = __builtin_amdgcn_mfma_f32_16x16x32_bf16(af, bf, acc[mt][nt], 0, 0, 0);
                }
            }
        }
        __syncthreads();
        cur ^= 1;
    }

    float* Op = Opart + ((size_t)(blockIdx.z * NB + b) * CAP) * DDIM;
    #pragma unroll
    for (int mt = 0; mt < 5; ++mt)
        #pragma unroll
        for (int nt = 0; nt < 4; ++nt)
            #pragma unroll
            for (int v = 0; v < 4; ++v) {
                int m = mt * 16 + q * 4 + v;
                Op[(size_t)m * DDIM + n0 + nt * 16 + r] = acc[mt][nt][v];
            }
}

// ---------------- reduce z=16 -> Out rows m<CAP (rest stays memset 0) -------
__global__ __launch_bounds__(256) void out_red(const float* __restrict__ Opart,
                                               float* __restrict__ Out)
{
    size_t i4 = (size_t)blockIdx.x * 256 + threadIdx.x;   // over 8*80*1024/4
    const size_t SL = (size_t)NB * CAP * DDIM;
    float4 s = *(const float4*)&Opart[i4 * 4];
    #pragma unroll
    for (int z = 1; z < 16; ++z) {
        float4 v = *(const float4*)&Opart[(size_t)z * SL + i4 * 4];
        s.x += v.x; s.y += v.y; s.z += v.z; s.w += v.w;
    }
    size_t i = i4 * 4;
    size_t b = i / ((size_t)CAP * DDIM);
    size_t rem = i % ((size_t)CAP * DDIM);
    size_t m = rem / DDIM, d = rem % DDIM;
    *(float4*)&Out[(b * NTOK + m) * DDIM + d] = s;
}

extern "C" void kernel_launch(void* const* d_in, const int* in_sizes, int n_in,
                              void* d_out, int out_size, void* d_ws, size_t ws_size,
                              hipStream_t stream) {
    const float* X  = (const float*)d_in[0];
    const int*   Y  = (const int*)d_in[1];
    const float* W1 = (const float*)d_in[2];
    const float* W2 = (const float*)d_in[3];
    float* Out = (float*)d_out;

    // ws: Hid bf16 @0 (5.25 MB) | Hpart @8MiB (42 MB, z=4) | Opart @64MiB (42 MB, z=16)
    uint8_t* ws = (uint8_t*)d_ws;
    __bf16* Hid   = (__bf16*)ws;
    float*  Hpart = (float*)(ws + (8u  << 20));
    float*  Opart = (float*)(ws + (64u << 20));

    // rows m >= CAP of Out must be exactly zero.
    hipMemsetAsync(d_out, 0, (size_t)out_size * sizeof(float), stream);

    moe_g1<<<dim3(HDIM / 512, NB, 4),  512, 0, stream>>>(X, Y, W1, Hpart);
    gelu_red<<<dim3(NB * CAP * HDIM / 4 / 256), 256, 0, stream>>>(Hpart, Hid);
    moe_g2<<<dim3(DDIM / 512, NB, 16), 512, 0, stream>>>(Hid, Y, W2, Opart);
    out_red<<<dim3(NB * CAP * DDIM / 4 / 256), 256, 0, stream>>>(Opart, Out);
}

// Round 6
// 477.300 us; speedup vs baseline: 1.0560x; 1.0560x over previous
//
#include <hip/hip_runtime.h>
#include <hip/hip_bf16.h>

#define NB   8
#define NTOK 1024
#define DDIM 1024
#define NEXP 16
#define HDIM 4096
#define CAP  80
#define BK   64

using bf16x8 = __attribute__((ext_vector_type(8))) __bf16;
using bf16x4 = __attribute__((ext_vector_type(4))) __bf16;
using f32x4  = __attribute__((ext_vector_type(4))) float;

// ---------------- GEMM1 + exact GELU ----------------
// Hid[b][m][h] = gelu(sum_k X[b][m][k] * W1[e][k][h]),  m<80, bf16 out.
// Block: 256 thr = 4 waves, BN=64 (1 n-tile of 16 per wave), all M=80 (5 m-tiles).
// A (X): LDS-staged bf16 [80][BK+8]; B (W1): direct global->reg frags (no LDS).
// NOTE: empirical best across 6 structural variants (473 µs); W-load path,
// occupancy, atomics, and barrier-count changes all measured neutral-or-worse.
__global__ __launch_bounds__(256) void moe_g1(
    const float* __restrict__ X, const int* __restrict__ Y,
    const float* __restrict__ W1, __bf16* __restrict__ Hid)
{
    const int b     = blockIdx.y;
    const int e     = Y[b] & (NEXP - 1);
    const int nbase = blockIdx.x * 64;
    const int tid   = threadIdx.x;
    const int w     = tid >> 6;       // wave 0..3
    const int l     = tid & 63;
    const int q     = l >> 4;         // quad 0..3
    const int r     = l & 15;
    const int n     = nbase + w * 16 + r;

    __shared__ __bf16 As[CAP][BK + 8];   // pad 8 bf16 = 16B -> conflict-free b64 wr / b128 rd

    const float* Xb  = X  + (size_t)b * NTOK * DDIM;
    const float* W1e = W1 + (size_t)e * DDIM * HDIM;

    f32x4 acc[5];
    #pragma unroll
    for (int i = 0; i < 5; ++i) acc[i] = f32x4{0.f, 0.f, 0.f, 0.f};

    for (int k0 = 0; k0 < DDIM; k0 += BK) {
        // ---- B fragment loads first (global fp32, coalesced across lanes in n)
        float bv[16];
        const float* bp = W1e + (size_t)(k0 + q * 8) * HDIM + n;
        #pragma unroll
        for (int s = 0; s < 2; ++s)
            #pragma unroll
            for (int j = 0; j < 8; ++j)
                bv[s * 8 + j] = bp[(size_t)(s * 32 + j) * HDIM];

        // ---- stage A chunk (fp32 -> bf16)
        __syncthreads();
        #pragma unroll
        for (int it = 0; it < 5; ++it) {
            int i   = tid + 256 * it;        // 0..1279
            int row = i >> 4, kg = i & 15;
            float4 v = *(const float4*)&Xb[(size_t)row * DDIM + k0 + kg * 4];
            bf16x4 p = {(__bf16)v.x, (__bf16)v.y, (__bf16)v.z, (__bf16)v.w};
            *(bf16x4*)&As[row][kg * 4] = p;
        }
        __syncthreads();

        // ---- MFMA: 2 k-steps of 32, 5 m-tiles
        #pragma unroll
        for (int s = 0; s < 2; ++s) {
            bf16x8 bf;
            #pragma unroll
            for (int j = 0; j < 8; ++j) bf[j] = (__bf16)bv[s * 8 + j];
            #pragma unroll
            for (int mt = 0; mt < 5; ++mt) {
                bf16x8 af = *(const bf16x8*)&As[mt * 16 + r][s * 32 + q * 8];
                acc[mt] = __builtin_amdgcn_mfma_f32_16x16x32_bf16(af, bf, acc[mt], 0, 0, 0);
            }
        }
    }

    // ---- epilogue: exact GELU, bf16 store. C/D layout: col=l&15, row=q*4+reg.
    __bf16* Hb = Hid + (size_t)b * CAP * HDIM;
    #pragma unroll
    for (int mt = 0; mt < 5; ++mt)
        #pragma unroll
        for (int v = 0; v < 4; ++v) {
            int m = mt * 16 + q * 4 + v;
            float x = acc[mt][v];
            float g = 0.5f * x * (1.0f + erff(x * 0.70710678118654752f));
            Hb[(size_t)m * HDIM + n] = (__bf16)g;
        }
}

// ---------------- GEMM2 ----------------
// Out[b][m][d] += sum_h Hid[b][m][h] * W2[e][h][d]; K=4096 split 4 (blockIdx.z),
// fp32 atomicAdd into zeroed Out.
__global__ __launch_bounds__(256) void moe_g2(
    const __bf16* __restrict__ Hid, const int* __restrict__ Y,
    const float* __restrict__ W2, float* __restrict__ Out)
{
    const int b     = blockIdx.y;
    const int e     = Y[b] & (NEXP - 1);
    const int nbase = blockIdx.x * 64;
    const int kz    = blockIdx.z * (HDIM / 4);
    const int tid   = threadIdx.x;
    const int w     = tid >> 6;
    const int l     = tid & 63;
    const int q     = l >> 4;
    const int r     = l & 15;
    const int n     = nbase + w * 16 + r;

    __shared__ __bf16 As[CAP][BK + 8];

    const __bf16* Hb  = Hid + (size_t)b * CAP * HDIM;
    const float*  W2e = W2  + (size_t)e * HDIM * DDIM;

    f32x4 acc[5];
    #pragma unroll
    for (int i = 0; i < 5; ++i) acc[i] = f32x4{0.f, 0.f, 0.f, 0.f};

    for (int k0 = kz; k0 < kz + HDIM / 4; k0 += BK) {
        float bv[16];
        const float* bp = W2e + (size_t)(k0 + q * 8) * DDIM + n;
        #pragma unroll
        for (int s = 0; s < 2; ++s)
            #pragma unroll
            for (int j = 0; j < 8; ++j)
                bv[s * 8 + j] = bp[(size_t)(s * 32 + j) * DDIM];

        __syncthreads();
        #pragma unroll
        for (int it = 0; it < 5; ++it) {
            int i   = tid + 256 * it;
            int row = i >> 4, kg = i & 15;
            uint2 v = *(const uint2*)&Hb[(size_t)row * HDIM + k0 + kg * 4]; // 4 bf16
            *(uint2*)&As[row][kg * 4] = v;
        }
        __syncthreads();

        #pragma unroll
        for (int s = 0; s < 2; ++s) {
            bf16x8 bf;
            #pragma unroll
            for (int j = 0; j < 8; ++j) bf[j] = (__bf16)bv[s * 8 + j];
            #pragma unroll
            for (int mt = 0; mt < 5; ++mt) {
                bf16x8 af = *(const bf16x8*)&As[mt * 16 + r][s * 32 + q * 8];
                acc[mt] = __builtin_amdgcn_mfma_f32_16x16x32_bf16(af, bf, acc[mt], 0, 0, 0);
            }
        }
    }

    float* Ob = Out + (size_t)b * NTOK * DDIM;
    #pragma unroll
    for (int mt = 0; mt < 5; ++mt)
        #pragma unroll
        for (int v = 0; v < 4; ++v) {
            int m = mt * 16 + q * 4 + v;
            atomicAdd(&Ob[(size_t)m * DDIM + n], acc[mt][v]);
        }
}

extern "C" void kernel_launch(void* const* d_in, const int* in_sizes, int n_in,
                              void* d_out, int out_size, void* d_ws, size_t ws_size,
                              hipStream_t stream) {
    const float* X  = (const float*)d_in[0];
    const int*   Y  = (const int*)d_in[1];
    const float* W1 = (const float*)d_in[2];
    const float* W2 = (const float*)d_in[3];
    float*  Out = (float*)d_out;
    __bf16* Hid = (__bf16*)d_ws;   // 8*80*4096*2 = 5.24 MB

    // rows n >= CAP must be exactly zero; also the atomicAdd base for split-K.
    hipMemsetAsync(d_out, 0, (size_t)out_size * sizeof(float), stream);

    moe_g1<<<dim3(HDIM / 64, NB), 256, 0, stream>>>(X, Y, W1, Hid);
    moe_g2<<<dim3(DDIM / 64, NB, 4), 256, 0, stream>>>(Hid, Y, W2, Out);
}